// Round 4
// baseline (1101.129 us; speedup 1.0000x reference)
//
#include <hip/hip_runtime.h>

// CRF log-likelihood: B=256, S=2048, L=64, START=62, END=63.
// One wave per batch element; lane i owns state i. Probability domain:
//   E_{s+1}[i] = l_s[i] * sum_j P[i][j] * E_s[j],  P = exp(T), l = exp(logit).
// P held as 32 packed-f16 VGPRs per lane (low pressure -> no remat/spill).
// All-to-all: E -> f16, pair-packed via DPP quad_perm, 32 v_readlane (SGPR),
// 32 v_dot2_f32_f16. No LDS, no barriers on the critical path.
// Per-step renorm: true wave-max via 6-stage DPP butterfly, power-of-2 scale
// from exponent bits (exact), integer log2 accumulator D.

#define Bsz 256
#define Ssz 2048
#define START_ 62
#define END_ 63

typedef __attribute__((ext_vector_type(2))) _Float16 half2v;

__device__ __forceinline__ unsigned h16bits(float x) {
    _Float16 h = (_Float16)x;
    return (unsigned)__builtin_bit_cast(unsigned short, h);
}

__device__ __forceinline__ unsigned pack_h2(float x, float y) {
    half2v h;
    h.x = (_Float16)x;
    h.y = (_Float16)y;
    return __builtin_bit_cast(unsigned, h);
}

__device__ __forceinline__ float dot2h(unsigned a, unsigned b, float c) {
#if __has_builtin(__builtin_amdgcn_fdot2)
    return __builtin_amdgcn_fdot2(__builtin_bit_cast(half2v, a),
                                  __builtin_bit_cast(half2v, b), c, false);
#else
    half2v ha = __builtin_bit_cast(half2v, a);
    half2v hb = __builtin_bit_cast(half2v, b);
    c = __builtin_fmaf((float)ha.x, (float)hb.x, c);
    return __builtin_fmaf((float)ha.y, (float)hb.y, c);
#endif
}

template <int CTRL>
__device__ __forceinline__ float dpp_max(float v) {
    int t = __builtin_amdgcn_update_dpp(__float_as_int(v), __float_as_int(v),
                                        CTRL, 0xf, 0xf, false);
    return fmaxf(v, __int_as_float(t));
}

// After this, lane 63 holds max over all 64 lanes.
__device__ __forceinline__ float wave_max63(float v) {
    v = dpp_max<0x111>(v);  // row_shr:1
    v = dpp_max<0x112>(v);  // row_shr:2
    v = dpp_max<0x114>(v);  // row_shr:4
    v = dpp_max<0x118>(v);  // row_shr:8
    v = dpp_max<0x142>(v);  // row_bcast:15
    v = dpp_max<0x143>(v);  // row_bcast:31
    return v;
}

__device__ __forceinline__ float wave_sum(float v) {
#pragma unroll
    for (int m = 32; m >= 1; m >>= 1) v += __shfl_xor(v, m, 64);
    return v;
}

__global__ __launch_bounds__(64, 1)
void crf_kernel(const float* __restrict__ logits,
                const float* __restrict__ transition,
                const int* __restrict__ labels,
                const int* __restrict__ lens,
                float* __restrict__ out)
{
    const int b    = blockIdx.x;
    const int lane = threadIdx.x;
    const float L2E = 1.4426950408889634f;
    const float LN2 = 0.6931471805599453f;

    const int len = lens[b];                       // 1..2048, wave-uniform
    const float* lrow = logits + (size_t)b * (Ssz * 64);

    // P[lane][j] = exp(T[lane][j]) as 32 packed f16 pairs (~32 VGPRs).
    unsigned P2[32];
#pragma unroll
    for (int k = 0; k < 32; ++k) {
        float p0 = __builtin_amdgcn_exp2f(transition[lane * 64 + 2 * k]     * L2E);
        float p1 = __builtin_amdgcn_exp2f(transition[lane * 64 + 2 * k + 1] * L2E);
        P2[k] = pack_h2(p0, p1);
    }

    float E = (lane == START_) ? 1.0f : 0.0f;      // prob-domain alpha (renormed)
    int   D = 0;                                   // exact log2 of removed scale

    // 8-deep rolling raw-logit prefetch (~1600 cyc slack >> HBM latency).
    float lgb[8];
#pragma unroll
    for (int d = 0; d < 8; ++d) {
        int s0 = (d < len) ? d : (len - 1);
        lgb[d] = lrow[s0 * 64 + lane];
    }

    for (int s = 0; s < len; s += 8) {
#pragma unroll
        for (int d = 0; d < 8; ++d) {
            if (s + d < len) {
                const float lg = lgb[d];
                int pf = s + 8 + d; pf = (pf < len) ? pf : (len - 1);
                lgb[d] = lrow[pf * 64 + lane];

                // Broadcast E as f16 pairs: even lane 2k (after quad_perm
                // neighbor-swap + pack) holds (E[2k], E[2k+1]).
                unsigned eb = h16bits(E);
                int nb = __builtin_amdgcn_update_dpp(0, (int)eb, 0xB1, 0xf, 0xf,
                                                     true);  // quad_perm [1,0,3,2]
                unsigned packed = eb | ((unsigned)nb << 16);

                float a0 = 0.f, a1 = 0.f, a2 = 0.f, a3 = 0.f;
                float a4 = 0.f, a5 = 0.f, a6 = 0.f, a7 = 0.f;
#pragma unroll
                for (int k = 0; k < 32; k += 8) {
                    unsigned s0 = (unsigned)__builtin_amdgcn_readlane((int)packed, 2 * k);
                    unsigned s1 = (unsigned)__builtin_amdgcn_readlane((int)packed, 2 * k + 2);
                    unsigned s2 = (unsigned)__builtin_amdgcn_readlane((int)packed, 2 * k + 4);
                    unsigned s3 = (unsigned)__builtin_amdgcn_readlane((int)packed, 2 * k + 6);
                    unsigned s4 = (unsigned)__builtin_amdgcn_readlane((int)packed, 2 * k + 8);
                    unsigned s5 = (unsigned)__builtin_amdgcn_readlane((int)packed, 2 * k + 10);
                    unsigned s6 = (unsigned)__builtin_amdgcn_readlane((int)packed, 2 * k + 12);
                    unsigned s7 = (unsigned)__builtin_amdgcn_readlane((int)packed, 2 * k + 14);
                    a0 = dot2h(s0, P2[k + 0], a0);
                    a1 = dot2h(s1, P2[k + 1], a1);
                    a2 = dot2h(s2, P2[k + 2], a2);
                    a3 = dot2h(s3, P2[k + 3], a3);
                    a4 = dot2h(s4, P2[k + 4], a4);
                    a5 = dot2h(s5, P2[k + 5], a5);
                    a6 = dot2h(s6, P2[k + 6], a6);
                    a7 = dot2h(s7, P2[k + 7], a7);
                }
                const float y = ((a0 + a1) + (a2 + a3)) + ((a4 + a5) + (a6 + a7));

                const float l  = __builtin_amdgcn_exp2f(lg * L2E);
                const float Ey = y * l;

                // Power-of-2 renorm by true wave max (pins max into [1,2)).
                const float m  = wave_max63(Ey);
                const int   mb = __builtin_amdgcn_readlane(__float_as_int(m), 63);
                const int   ee = (mb >> 23) & 0xff;            // biased exponent
                const float scale = __int_as_float((254 - ee) << 23);  // 2^(127-ee)
                E  = Ey * scale;
                D += ee - 127;
            }
        }
    }

    // norm = ln2 * (D + log2(sum_i E_i * exp(T[END,i])))
    const float Pend = __builtin_amdgcn_exp2f(transition[END_ * 64 + lane] * L2E);
    const float tot  = wave_sum(E * Pend);
    const float norm = LN2 * ((float)D + __builtin_amdgcn_logf(tot));

    // Gold path score (exact, as in round 1).
    const int* lab = labels + (size_t)b * Ssz;
    float g = 0.0f;
    for (int s = lane; s < len; s += 64) {
        const int l1 = lab[s];
        const int l0 = (s == 0) ? START_ : lab[s - 1];
        g += lrow[s * 64 + l1] + transition[l1 * 64 + l0];
    }
    if (lane == 0) g += transition[END_ * 64 + lab[len - 1]];
    const float gold = wave_sum(g);

    if (lane == 0) out[b] = gold - norm;
}

extern "C" void kernel_launch(void* const* d_in, const int* in_sizes, int n_in,
                              void* d_out, int out_size, void* d_ws, size_t ws_size,
                              hipStream_t stream) {
    const float* logits     = (const float*)d_in[0];
    const float* transition = (const float*)d_in[1];
    const int*   labels     = (const int*)d_in[2];
    const int*   lens       = (const int*)d_in[3];
    float*       out        = (float*)d_out;

    crf_kernel<<<dim3(Bsz), dim3(64), 0, stream>>>(
        logits, transition, labels, lens, out);
}

// Round 5
// 827.491 us; speedup vs baseline: 1.3307x; 1.3307x over previous
//
#include <hip/hip_runtime.h>

// CRF log-likelihood: B=256, S=2048, L=64, START=62, END=63.
// One wave per batch element; lane i owns state i. Probability domain:
//   E_{s+1}[i] = l_s[i] * sum_j P[i][j] * E_s[j],  P = exp(T), l = exp(logit).
// P held as 32 packed-f16 VGPRs per lane, PINNED via opaque inline asm so the
// register allocator cannot rematerialize exp2(load(T)) inside the loop
// (round-4 pathology: VGPR_Count=32 -> P recomputed every step, ~700 cyc).
// All-to-all: E -> f16, pair-packed via DPP quad_perm, 32 v_readlane (SGPR),
// 32 v_dot2_f32_f16. No LDS, no barriers. Per-step renorm: wave-max via
// 6-stage DPP butterfly, exact power-of-2 scale, integer log2 accumulator D.
// Main loop is branch-free (len & ~7) + separate <=7-step tail.

#define Bsz 256
#define Ssz 2048
#define START_ 62
#define END_ 63

typedef __attribute__((ext_vector_type(2))) _Float16 half2v;

__device__ __forceinline__ unsigned h16bits(float x) {
    _Float16 h = (_Float16)x;
    return (unsigned)__builtin_bit_cast(unsigned short, h);
}

__device__ __forceinline__ unsigned pack_h2(float x, float y) {
    half2v h;
    h.x = (_Float16)x;
    h.y = (_Float16)y;
    return __builtin_bit_cast(unsigned, h);
}

__device__ __forceinline__ float dot2h(unsigned a, unsigned b, float c) {
#if __has_builtin(__builtin_amdgcn_fdot2)
    return __builtin_amdgcn_fdot2(__builtin_bit_cast(half2v, a),
                                  __builtin_bit_cast(half2v, b), c, false);
#else
    half2v ha = __builtin_bit_cast(half2v, a);
    half2v hb = __builtin_bit_cast(half2v, b);
    c = __builtin_fmaf((float)ha.x, (float)hb.x, c);
    return __builtin_fmaf((float)ha.y, (float)hb.y, c);
#endif
}

template <int CTRL>
__device__ __forceinline__ float dpp_max(float v) {
    int t = __builtin_amdgcn_update_dpp(__float_as_int(v), __float_as_int(v),
                                        CTRL, 0xf, 0xf, false);
    return fmaxf(v, __int_as_float(t));
}

// After this, lane 63 holds max over all 64 lanes.
__device__ __forceinline__ float wave_max63(float v) {
    v = dpp_max<0x111>(v);  // row_shr:1
    v = dpp_max<0x112>(v);  // row_shr:2
    v = dpp_max<0x114>(v);  // row_shr:4
    v = dpp_max<0x118>(v);  // row_shr:8
    v = dpp_max<0x142>(v);  // row_bcast:15
    v = dpp_max<0x143>(v);  // row_bcast:31
    return v;
}

__device__ __forceinline__ float wave_sum(float v) {
#pragma unroll
    for (int m = 32; m >= 1; m >>= 1) v += __shfl_xor(v, m, 64);
    return v;
}

// One recurrence step. lg = raw logit for this lane's state (loaded >=8 steps
// ago, so exp2 here is off the critical path). Updates E (renormed prob alpha)
// and D (exact power-of-2 scale removed so far, in log2 units).
#define CRF_STEP(LG)                                                          \
    {                                                                         \
        const float l_ = __builtin_amdgcn_exp2f((LG) * L2E);                  \
        const unsigned eb_ = h16bits(E);                                      \
        const int nb_ = __builtin_amdgcn_update_dpp(0, (int)eb_, 0xB1, 0xf,   \
                                                    0xf, true);               \
        const unsigned packed_ = eb_ | ((unsigned)nb_ << 16);                 \
        float a0 = 0.f, a1 = 0.f, a2 = 0.f, a3 = 0.f;                         \
        float a4 = 0.f, a5 = 0.f, a6 = 0.f, a7 = 0.f;                         \
        _Pragma("unroll")                                                     \
        for (int k = 0; k < 32; k += 8) {                                     \
            unsigned t0 = (unsigned)__builtin_amdgcn_readlane((int)packed_, 2 * k);      \
            unsigned t1 = (unsigned)__builtin_amdgcn_readlane((int)packed_, 2 * k + 2);  \
            unsigned t2 = (unsigned)__builtin_amdgcn_readlane((int)packed_, 2 * k + 4);  \
            unsigned t3 = (unsigned)__builtin_amdgcn_readlane((int)packed_, 2 * k + 6);  \
            unsigned t4 = (unsigned)__builtin_amdgcn_readlane((int)packed_, 2 * k + 8);  \
            unsigned t5 = (unsigned)__builtin_amdgcn_readlane((int)packed_, 2 * k + 10); \
            unsigned t6 = (unsigned)__builtin_amdgcn_readlane((int)packed_, 2 * k + 12); \
            unsigned t7 = (unsigned)__builtin_amdgcn_readlane((int)packed_, 2 * k + 14); \
            a0 = dot2h(t0, P2[k + 0], a0);                                    \
            a1 = dot2h(t1, P2[k + 1], a1);                                    \
            a2 = dot2h(t2, P2[k + 2], a2);                                    \
            a3 = dot2h(t3, P2[k + 3], a3);                                    \
            a4 = dot2h(t4, P2[k + 4], a4);                                    \
            a5 = dot2h(t5, P2[k + 5], a5);                                    \
            a6 = dot2h(t6, P2[k + 6], a6);                                    \
            a7 = dot2h(t7, P2[k + 7], a7);                                    \
        }                                                                     \
        const float y_ = ((a0 + a1) + (a2 + a3)) + ((a4 + a5) + (a6 + a7));   \
        const float Ey_ = y_ * l_;                                            \
        const float m_ = wave_max63(Ey_);                                     \
        const int mb_ = __builtin_amdgcn_readlane(__float_as_int(m_), 63);    \
        const int ee_ = (mb_ >> 23) & 0xff;                                   \
        const float sc_ = __int_as_float((254 - ee_) << 23);                  \
        E = Ey_ * sc_;                                                        \
        D += ee_ - 127;                                                       \
    }

__global__ __launch_bounds__(64, 1)
void crf_kernel(const float* __restrict__ logits,
                const float* __restrict__ transition,
                const int* __restrict__ labels,
                const int* __restrict__ lens,
                float* __restrict__ out)
{
    const int b    = blockIdx.x;
    const int lane = threadIdx.x;
    const float L2E = 1.4426950408889634f;
    const float LN2 = 0.6931471805599453f;

    const int len = lens[b];                       // 1..2048, wave-uniform
    const float* lrow = logits + (size_t)b * (Ssz * 64);

    // P[lane][j] = exp(T[lane][j]) as 32 packed f16 pairs.
    unsigned P2[32];
#pragma unroll
    for (int k = 0; k < 32; ++k) {
        float p0 = __builtin_amdgcn_exp2f(transition[lane * 64 + 2 * k]     * L2E);
        float p1 = __builtin_amdgcn_exp2f(transition[lane * 64 + 2 * k + 1] * L2E);
        P2[k] = pack_h2(p0, p1);
    }
    // Pin each P2 value: opaque def -> cannot be rematerialized by RA.
#pragma unroll
    for (int k = 0; k < 32; ++k) asm volatile("" : "+v"(P2[k]));

    float E = (lane == START_) ? 1.0f : 0.0f;      // prob-domain alpha (renormed)
    int   D = 0;                                   // exact log2 of removed scale

    // 8-deep rolling raw-logit prefetch (coalesced 256 B/row).
    float lgb[8];
#pragma unroll
    for (int d = 0; d < 8; ++d) {
        int s0 = (d < len) ? d : (len - 1);
        lgb[d] = lrow[s0 * 64 + lane];
    }

    const int len8 = len & ~7;
    for (int s = 0; s < len8; s += 8) {
#pragma unroll
        for (int d = 0; d < 8; ++d) {
            const float lg = lgb[d];
            int pf = s + 8 + d;
            pf = (pf < len) ? pf : (len - 1);
            lgb[d] = lrow[pf * 64 + lane];         // prefetch 8 ahead
            CRF_STEP(lg);
        }
    }
    const int rem = len - len8;
    for (int d = 0; d < rem; ++d) {                // <=7 iterations
        const float lg = lgb[d];
        CRF_STEP(lg);
    }

    // norm = ln2 * (D + log2(sum_i E_i * exp(T[END,i])))
    const float Pend = __builtin_amdgcn_exp2f(transition[END_ * 64 + lane] * L2E);
    const float tot  = wave_sum(E * Pend);
    const float norm = LN2 * ((float)D + __builtin_amdgcn_logf(tot));

    // Gold path score (exact).
    const int* lab = labels + (size_t)b * Ssz;
    float g = 0.0f;
    for (int s = lane; s < len; s += 64) {
        const int l1 = lab[s];
        const int l0 = (s == 0) ? START_ : lab[s - 1];
        g += lrow[s * 64 + l1] + transition[l1 * 64 + l0];
    }
    if (lane == 0) g += transition[END_ * 64 + lab[len - 1]];
    const float gold = wave_sum(g);

    if (lane == 0) out[b] = gold - norm;
}

extern "C" void kernel_launch(void* const* d_in, const int* in_sizes, int n_in,
                              void* d_out, int out_size, void* d_ws, size_t ws_size,
                              hipStream_t stream) {
    const float* logits     = (const float*)d_in[0];
    const float* transition = (const float*)d_in[1];
    const int*   labels     = (const int*)d_in[2];
    const int*   lens       = (const int*)d_in[3];
    float*       out        = (float*)d_out;

    crf_kernel<<<dim3(Bsz), dim3(64), 0, stream>>>(
        logits, transition, labels, lens, out);
}

// Round 7
// 641.423 us; speedup vs baseline: 1.7167x; 1.2901x over previous
//
#include <hip/hip_runtime.h>

// CRF log-likelihood: B=256, S=2048, L=64, START=62, END=63.
// One wave per batch element; lane i owns state i. Probability domain:
//   E_{s+1}[i] = l_s[i] * sum_j P[i][j] * E_s[j],  P = exp(T), l = exp(logit).
//
// Round-4/5 lesson: the RA will NOT keep a 32-reg constant array live across
// this loop (remat -> ~700 cyc/step; asm-pin -> scratch spill ~500 cyc/step).
// So P lives in LDS (packed f16 pairs, row stride 36 dwords: b128 reads are
// bank-conflict-free), re-read each step via 8x ds_read_b128 — independent of
// E, so they overlap the VALU phase. asm-opaque address stops LICM hoisting.
// Single wave per block -> no barriers at all.
//
// Renorm per step by a PROXY: exponent of f32 Ey at lane 0 (one v_readlane,
// no butterfly). Ey[0] is within ~2^±14 of the true max (P row 0 strictly
// positive, l0 bounded); centering the proxy at 2^-8 keeps E in f16 range.
// Exact power-of-2 bookkeeping in integer D.

#define Bsz 256
#define Ssz 2048
#define START_ 62
#define END_ 63
#define PSTRIDE 36   // dwords per LDS row: 32 data + 4 pad (conflict-free b128)

typedef __attribute__((ext_vector_type(2))) _Float16 half2v;

__device__ __forceinline__ unsigned pack_pkrtz(float a, float b) {
    auto h = __builtin_amdgcn_cvt_pkrtz(a, b);   // __fp16 ext_vector(2)
    return __builtin_bit_cast(unsigned, h);
}

__device__ __forceinline__ float dot2h(unsigned a, unsigned b, float c) {
#if __has_builtin(__builtin_amdgcn_fdot2)
    return __builtin_amdgcn_fdot2(__builtin_bit_cast(half2v, a),
                                  __builtin_bit_cast(half2v, b), c, false);
#else
    half2v ha = __builtin_bit_cast(half2v, a);
    half2v hb = __builtin_bit_cast(half2v, b);
    c = __builtin_fmaf((float)ha.x, (float)hb.x, c);
    return __builtin_fmaf((float)ha.y, (float)hb.y, c);
#endif
}

__device__ __forceinline__ float wave_sum(float v) {
#pragma unroll
    for (int m = 32; m >= 1; m >>= 1) v += __shfl_xor(v, m, 64);
    return v;
}

// One recurrence step. LG = raw logit (loaded >=8 steps ago). Updates E
// (renormed prob-domain alpha, f32) and D (exact log2 of removed scale).
#define CRF_STEP(LG)                                                           \
    {                                                                          \
        const float l_ = __builtin_amdgcn_exp2f((LG) * L2E);                   \
        const int nbi_ = __builtin_amdgcn_update_dpp(                          \
            0, __float_as_int(E), 0xB1, 0xf, 0xf, true); /* quad_perm 1,0,3,2*/\
        const unsigned packed_ = pack_pkrtz(E, __int_as_float(nbi_));          \
        unsigned off_ = (unsigned)(lane * (PSTRIDE * 4));                      \
        asm volatile("" : "+v"(off_)); /* defeat LICM: address opaque */       \
        const uint4* prow_ = (const uint4*)((const char*)Psh + off_);          \
        float c0 = 0.f, c1 = 0.f, c2 = 0.f, c3 = 0.f;                          \
        float c4 = 0.f, c5 = 0.f, c6 = 0.f, c7 = 0.f;                          \
        _Pragma("unroll")                                                      \
        for (int k8 = 0; k8 < 8; ++k8) {                                       \
            const uint4 q_ = prow_[k8];                                        \
            const unsigned t0 = (unsigned)__builtin_amdgcn_readlane(           \
                (int)packed_, 8 * k8 + 0);                                     \
            const unsigned t1 = (unsigned)__builtin_amdgcn_readlane(           \
                (int)packed_, 8 * k8 + 2);                                     \
            const unsigned t2 = (unsigned)__builtin_amdgcn_readlane(           \
                (int)packed_, 8 * k8 + 4);                                     \
            const unsigned t3 = (unsigned)__builtin_amdgcn_readlane(           \
                (int)packed_, 8 * k8 + 6);                                     \
            if (k8 & 1) {                                                      \
                c4 = dot2h(t0, q_.x, c4);                                      \
                c5 = dot2h(t1, q_.y, c5);                                      \
                c6 = dot2h(t2, q_.z, c6);                                      \
                c7 = dot2h(t3, q_.w, c7);                                      \
            } else {                                                           \
                c0 = dot2h(t0, q_.x, c0);                                      \
                c1 = dot2h(t1, q_.y, c1);                                      \
                c2 = dot2h(t2, q_.z, c2);                                      \
                c3 = dot2h(t3, q_.w, c3);                                      \
            }                                                                  \
        }                                                                      \
        const float y_ = ((c0 + c1) + (c2 + c3)) + ((c4 + c5) + (c6 + c7));    \
        const float Ey_ = y_ * l_;                                             \
        const int pb_ = __builtin_amdgcn_readlane(__float_as_int(Ey_), 0);     \
        const int ee_ = (pb_ >> 23) & 0xff;   /* proxy biased exponent */      \
        const float sc_ = __int_as_float((246 - ee_) << 23); /* 2^(119-ee) */  \
        E = Ey_ * sc_;                                                         \
        D += ee_ - 119;                                                        \
    }

__global__ __launch_bounds__(64, 1)
void crf_kernel(const float* __restrict__ logits,
                const float* __restrict__ transition,
                const int* __restrict__ labels,
                const int* __restrict__ lens,
                float* __restrict__ out)
{
    const int b    = blockIdx.x;
    const int lane = threadIdx.x;
    const float L2E = 1.4426950408889634f;
    const float LN2 = 0.6931471805599453f;

    __shared__ unsigned Psh[64 * PSTRIDE];

    const int len = lens[b];                       // 1..2048, wave-uniform
    const float* lrow = logits + (size_t)b * (Ssz * 64);

    // Stage P[lane][j] = exp(T[lane][j]) as packed f16 pairs into LDS.
    // One-time; write bank conflicts irrelevant. No barrier needed (1 wave).
#pragma unroll
    for (int k = 0; k < 32; ++k) {
        float p0 = __builtin_amdgcn_exp2f(transition[lane * 64 + 2 * k]     * L2E);
        float p1 = __builtin_amdgcn_exp2f(transition[lane * 64 + 2 * k + 1] * L2E);
        Psh[lane * PSTRIDE + k] = pack_pkrtz(p0, p1);
    }
    asm volatile("s_waitcnt lgkmcnt(0)" ::: "memory");

    float E = (lane == START_) ? 1.0f : 0.0f;      // prob-domain alpha (renormed)
    int   D = 0;                                   // exact log2 of removed scale

    // 8-deep rolling raw-logit prefetch (coalesced 256 B/row).
    float lgb[8];
#pragma unroll
    for (int d = 0; d < 8; ++d) {
        int s0 = (d < len) ? d : (len - 1);
        lgb[d] = lrow[s0 * 64 + lane];
    }

    const int len8 = len & ~7;
    for (int s = 0; s < len8; s += 8) {
#pragma unroll
        for (int d = 0; d < 8; ++d) {
            const float lg = lgb[d];
            int pf = s + 8 + d;
            pf = (pf < len) ? pf : (len - 1);
            lgb[d] = lrow[pf * 64 + lane];         // prefetch 8 ahead
            CRF_STEP(lg);
        }
    }
    const int rem = len - len8;
    for (int d = 0; d < rem; ++d) {                // <=7 iterations
        const float lg = lgb[d];
        CRF_STEP(lg);
    }

    // norm = ln2 * (D + log2(sum_i E_i * exp(T[END,i])))
    const float Pend = __builtin_amdgcn_exp2f(transition[END_ * 64 + lane] * L2E);
    const float tot  = wave_sum(E * Pend);
    const float norm = LN2 * ((float)D + __builtin_amdgcn_logf(tot));

    // Gold path score (exact).
    const int* lab = labels + (size_t)b * Ssz;
    float g = 0.0f;
    for (int s = lane; s < len; s += 64) {
        const int l1 = lab[s];
        const int l0 = (s == 0) ? START_ : lab[s - 1];
        g += lrow[s * 64 + l1] + transition[l1 * 64 + l0];
    }
    if (lane == 0) g += transition[END_ * 64 + lab[len - 1]];
    const float gold = wave_sum(g);

    if (lane == 0) out[b] = gold - norm;
}

extern "C" void kernel_launch(void* const* d_in, const int* in_sizes, int n_in,
                              void* d_out, int out_size, void* d_ws, size_t ws_size,
                              hipStream_t stream) {
    const float* logits     = (const float*)d_in[0];
    const float* transition = (const float*)d_in[1];
    const int*   labels     = (const int*)d_in[2];
    const int*   lens       = (const int*)d_in[3];
    float*       out        = (float*)d_out;

    crf_kernel<<<dim3(Bsz), dim3(64), 0, stream>>>(
        logits, transition, labels, lens, out);
}

// Round 8
// 538.000 us; speedup vs baseline: 2.0467x; 1.1922x over previous
//
#include <hip/hip_runtime.h>

// CRF log-likelihood: B=256, S=2048, L=64, START=62, END=63.
// One wave per batch element; lane i owns state i. Probability domain:
//   E_{s+1}[i] = l_s[i] * sum_j P[i][j] * E_s[j],  P = exp(T), l = exp(logit).
//
// P lives in LDS (packed f16 pairs, padded stride -> conflict-free b128) and
// is loaded into registers ONCE PER 8-STEP BLOCK (uint4 q[8], within-iteration
// live range; opaque base address defeats remat/CSE/hoist). Round-7 lesson:
// per-step ds_reads scheduled read->use exposed ~380 stall cyc/step.
// amdgpu_waves_per_eu(1,1): RA budget = full register file (rounds 4-7 showed
// the default occupancy target caps at ~64 VGPRs -> remat/spill disease).
//
// Renorm per step by PROXY: exponent of f32 Ey at lane 0 (one v_readlane).
// Centered at 2^-10: clamp headroom e^+18 above proxy, flush floor e^-9.7
// below (f16 RTZ saturates at 65504 -> graceful). Exact power-of-2
// bookkeeping in integer D.

#define Bsz 256
#define Ssz 2048
#define START_ 62
#define END_ 63
#define PSTRIDE 36   // dwords per LDS row: 32 data + 4 pad (conflict-free b128)

typedef __attribute__((ext_vector_type(2))) _Float16 half2v;

__device__ __forceinline__ unsigned pack_pkrtz(float a, float b) {
    auto h = __builtin_amdgcn_cvt_pkrtz(a, b);   // __fp16 ext_vector(2)
    return __builtin_bit_cast(unsigned, h);
}

__device__ __forceinline__ float dot2h(unsigned a, unsigned b, float c) {
#if __has_builtin(__builtin_amdgcn_fdot2)
    return __builtin_amdgcn_fdot2(__builtin_bit_cast(half2v, a),
                                  __builtin_bit_cast(half2v, b), c, false);
#else
    half2v ha = __builtin_bit_cast(half2v, a);
    half2v hb = __builtin_bit_cast(half2v, b);
    c = __builtin_fmaf((float)ha.x, (float)hb.x, c);
    return __builtin_fmaf((float)ha.y, (float)hb.y, c);
#endif
}

__device__ __forceinline__ float wave_sum(float v) {
#pragma unroll
    for (int m = 32; m >= 1; m >>= 1) v += __shfl_xor(v, m, 64);
    return v;
}

// One recurrence step; q[0..7] (this lane's P row, packed f16 pairs) must be
// in scope. LG = raw logit loaded >=8 steps ago. Updates E (renormed
// prob-domain alpha, f32) and D (exact log2 of removed scale).
#define CRF_STEP(LG)                                                           \
    {                                                                          \
        const float l_ = __builtin_amdgcn_exp2f((LG) * L2E);                   \
        const int nbi_ = __builtin_amdgcn_update_dpp(                          \
            0, __float_as_int(E), 0xB1, 0xf, 0xf, true); /* quad_perm 1,0,3,2*/\
        const unsigned packed_ = pack_pkrtz(E, __int_as_float(nbi_));          \
        float c0 = 0.f, c1 = 0.f, c2 = 0.f, c3 = 0.f;                          \
        float c4 = 0.f, c5 = 0.f, c6 = 0.f, c7 = 0.f;                          \
        _Pragma("unroll")                                                      \
        for (int k8 = 0; k8 < 8; ++k8) {                                       \
            const uint4 q_ = q[k8];                                            \
            const unsigned t0 = (unsigned)__builtin_amdgcn_readlane(           \
                (int)packed_, 8 * k8 + 0);                                     \
            const unsigned t1 = (unsigned)__builtin_amdgcn_readlane(           \
                (int)packed_, 8 * k8 + 2);                                     \
            const unsigned t2 = (unsigned)__builtin_amdgcn_readlane(           \
                (int)packed_, 8 * k8 + 4);                                     \
            const unsigned t3 = (unsigned)__builtin_amdgcn_readlane(           \
                (int)packed_, 8 * k8 + 6);                                     \
            if (k8 & 1) {                                                      \
                c4 = dot2h(t0, q_.x, c4);                                      \
                c5 = dot2h(t1, q_.y, c5);                                      \
                c6 = dot2h(t2, q_.z, c6);                                      \
                c7 = dot2h(t3, q_.w, c7);                                      \
            } else {                                                           \
                c0 = dot2h(t0, q_.x, c0);                                      \
                c1 = dot2h(t1, q_.y, c1);                                      \
                c2 = dot2h(t2, q_.z, c2);                                      \
                c3 = dot2h(t3, q_.w, c3);                                      \
            }                                                                  \
        }                                                                      \
        const float y_ = ((c0 + c1) + (c2 + c3)) + ((c4 + c5) + (c6 + c7));    \
        const float Ey_ = y_ * l_;                                             \
        const int pb_ = __builtin_amdgcn_readlane(__float_as_int(Ey_), 0);     \
        const int ee_ = (pb_ >> 23) & 0xff;   /* proxy biased exponent */      \
        const float sc_ = __int_as_float((244 - ee_) << 23); /* 2^(117-ee) */  \
        E = Ey_ * sc_;                                                         \
        D += ee_ - 117;                                                        \
    }

// Reload this lane's P row from LDS into q[8] through an opaque address
// (fresh per call -> loads cannot be hoisted/CSE'd/remat'd across blocks).
#define LOAD_QBLOCK()                                                          \
    {                                                                          \
        unsigned off_ = (unsigned)(lane * (PSTRIDE * 4));                      \
        asm volatile("" : "+v"(off_));                                         \
        const uint4* prow_ = (const uint4*)((const char*)Psh + off_);          \
        _Pragma("unroll")                                                      \
        for (int k8 = 0; k8 < 8; ++k8) q[k8] = prow_[k8];                      \
    }

__global__ __launch_bounds__(64)
__attribute__((amdgpu_waves_per_eu(1, 1)))
void crf_kernel(const float* __restrict__ logits,
                const float* __restrict__ transition,
                const int* __restrict__ labels,
                const int* __restrict__ lens,
                float* __restrict__ out)
{
    const int b    = blockIdx.x;
    const int lane = threadIdx.x;
    const float L2E = 1.4426950408889634f;
    const float LN2 = 0.6931471805599453f;

    __shared__ unsigned Psh[64 * PSTRIDE];

    const int len = lens[b];                       // 1..2048, wave-uniform
    const float* lrow = logits + (size_t)b * (Ssz * 64);

    // Stage P[lane][j] = exp(T[lane][j]) as packed f16 pairs into LDS.
    // One-time; no barrier needed (single wave).
#pragma unroll
    for (int k = 0; k < 32; ++k) {
        float p0 = __builtin_amdgcn_exp2f(transition[lane * 64 + 2 * k]     * L2E);
        float p1 = __builtin_amdgcn_exp2f(transition[lane * 64 + 2 * k + 1] * L2E);
        Psh[lane * PSTRIDE + k] = pack_pkrtz(p0, p1);
    }
    asm volatile("s_waitcnt lgkmcnt(0)" ::: "memory");

    float E = (lane == START_) ? 1.0f : 0.0f;      // prob-domain alpha (renormed)
    int   D = 0;                                   // exact log2 of removed scale

    // 8-deep rolling raw-logit prefetch (coalesced 256 B/row).
    float lgb[8];
#pragma unroll
    for (int d = 0; d < 8; ++d) {
        int s0 = (d < len) ? d : (len - 1);
        lgb[d] = lrow[s0 * 64 + lane];
    }

    uint4 q[8];
    const int len8 = len & ~7;
    for (int s = 0; s < len8; s += 8) {
        LOAD_QBLOCK();                             // 8x ds_read_b128 per 8 steps
#pragma unroll
        for (int d = 0; d < 8; ++d) {
            const float lg = lgb[d];
            int pf = s + 8 + d;
            pf = (pf < len) ? pf : (len - 1);
            lgb[d] = lrow[pf * 64 + lane];         // prefetch 8 ahead
            CRF_STEP(lg);
        }
    }
    const int rem = len - len8;
    if (rem) {
        LOAD_QBLOCK();
        for (int d = 0; d < rem; ++d) {            // <=7 iterations
            const float lg = lgb[d];
            CRF_STEP(lg);
        }
    }

    // norm = ln2 * (D + log2(sum_i E_i * exp(T[END,i])))
    const float Pend = __builtin_amdgcn_exp2f(transition[END_ * 64 + lane] * L2E);
    const float tot  = wave_sum(E * Pend);
    const float norm = LN2 * ((float)D + __builtin_amdgcn_logf(tot));

    // Gold path score (exact).
    const int* lab = labels + (size_t)b * Ssz;
    float g = 0.0f;
    for (int s = lane; s < len; s += 64) {
        const int l1 = lab[s];
        const int l0 = (s == 0) ? START_ : lab[s - 1];
        g += lrow[s * 64 + l1] + transition[l1 * 64 + l0];
    }
    if (lane == 0) g += transition[END_ * 64 + lab[len - 1]];
    const float gold = wave_sum(g);

    if (lane == 0) out[b] = gold - norm;
}

extern "C" void kernel_launch(void* const* d_in, const int* in_sizes, int n_in,
                              void* d_out, int out_size, void* d_ws, size_t ws_size,
                              hipStream_t stream) {
    const float* logits     = (const float*)d_in[0];
    const float* transition = (const float*)d_in[1];
    const int*   labels     = (const int*)d_in[2];
    const int*   lens       = (const int*)d_in[3];
    float*       out        = (float*)d_out;

    crf_kernel<<<dim3(Bsz), dim3(64), 0, stream>>>(
        logits, transition, labels, lens, out);
}